// Round 6
// baseline (43.727 us; speedup 1.0000x reference)
//
#include <hip/hip_runtime.h>
#include <math.h>

// FrequencyAdaptiveNorm: multi-scale (w=5,10,20) centered sliding-window
// normalization over L, softmax-weighted fusion.
// x: (B=32, L=2048, F=256) f32, weights: (3,) f32, out: same shape.
//
// v6: load-all-then-compute. Each thread owns one f-column for a TL=16
// chunk: 35 independent global loads (the whole x[l0-10 .. l0+TL+8] slice)
// are issued as one batch into registers, a compiler fence pins them above
// the compute, then all 16 outputs are pure register math (running sums,
// static indices, no ring shift). This removes the per-iteration load
// latency exposure that capped v4 (VGPR=28 -> ~2 loads in flight) without
// the structured-prefetch pessimization of v5.

#define B_ 32
#define L_ 2048
#define F_ 256
#define TL 16                 // outputs per thread; grid = (128, 32)
#define NV (TL + 19)          // loads per thread: x[l0-10 .. l0+TL+8]

__device__ __forceinline__ float fin(float v) {
    return isfinite(v) ? v : 0.0f;   // nan_to_num(nan=0, +inf=0, -inf=0)
}

// ---------------- interior: no bounds checks, batched loads ----------------
__device__ __forceinline__ void run_interior(const float* __restrict__ xb,
                                             float* __restrict__ ob,
                                             const int l0,
                                             const float ws5, const float ws10,
                                             const float ws20) {
    const float eps = 1e-5f;

    // v[d] = x[l0-10+d], d = 0..NV-1 — one flat load batch
    float v[NV];
#pragma unroll
    for (int d = 0; d < NV; ++d) v[d] = fin(xb[(l0 - 10 + d) * F_]);
    asm volatile("" ::: "memory");   // keep the load batch above the compute

    // running sums at j=l0: w5=v[8..12], w10=v[5..14], w20=v[0..19]
    float s5 = 0.f, q5 = 0.f, s10 = 0.f, q10 = 0.f, s20 = 0.f, q20 = 0.f;
#pragma unroll
    for (int d = 0; d < 20; ++d) { s20 += v[d]; q20 = fmaf(v[d], v[d], q20); }
#pragma unroll
    for (int d = 5; d < 15; ++d) { s10 += v[d]; q10 = fmaf(v[d], v[d], q10); }
#pragma unroll
    for (int d = 8; d < 13; ++d) { s5  += v[d]; q5  = fmaf(v[d], v[d], q5);  }

#pragma unroll
    for (int t = 0; t < TL; ++t) {
        const float xc = v[t + 10];
        float acc;
        {   // w=5
            const float mean  = s5 * 0.2f;
            const float mean2 = q5 * 0.2f;
            const float var   = fmaxf(fmaf(-mean, mean, mean2), 0.0f);
            acc = ws5 * ((xc - mean) * rsqrtf(var + eps));
        }
        {   // w=10
            const float mean  = s10 * 0.1f;
            const float mean2 = q10 * 0.1f;
            const float var   = fmaxf(fmaf(-mean, mean, mean2), 0.0f);
            acc = fmaf(ws10, (xc - mean) * rsqrtf(var + eps), acc);
        }
        {   // w=20
            const float mean  = s20 * 0.05f;
            const float mean2 = q20 * 0.05f;
            const float var   = fmaxf(fmaf(-mean, mean, mean2), 0.0f);
            acc = fmaf(ws20, (xc - mean) * rsqrtf(var + eps), acc);
        }
        ob[(l0 + t) * F_] = acc;

        // slide windows j -> j+1 (skip after the last output)
        if (t < TL - 1) {
            {
                const float a = v[t + 13], r = v[t + 8];
                const float d = a - r, p = a + r;
                s5 += d; q5 = fmaf(d, p, q5);
            }
            {
                const float a = v[t + 15], r = v[t + 5];
                const float d = a - r, p = a + r;
                s10 += d; q10 = fmaf(d, p, q10);
            }
            {
                const float a = v[t + 20], r = v[t];
                const float d = a - r, p = a + r;
                s20 += d; q20 = fmaf(d, p, q20);
            }
        }
    }
}

// ---------------- edge: checked path (2 of 128 chunks) ----------------
__device__ __forceinline__ void run_edge(const float* __restrict__ xb,
                                         float* __restrict__ ob,
                                         const int l0,
                                         const float ws5, const float ws10,
                                         const float ws20) {
    const float eps = 1e-5f;

    float ring[21];
#pragma unroll
    for (int d = 0; d < 21; ++d) {
        const int l = l0 - 10 + d;
        ring[d] = ((unsigned)l < (unsigned)L_) ? fin(xb[l * F_]) : 0.0f;
    }

    float s5 = 0.f, q5 = 0.f, s10 = 0.f, q10 = 0.f, s20 = 0.f, q20 = 0.f;
#pragma unroll
    for (int d = 0; d < 20; ++d) { s20 += ring[d]; q20 = fmaf(ring[d], ring[d], q20); }
#pragma unroll
    for (int d = 5; d < 15; ++d) { s10 += ring[d]; q10 = fmaf(ring[d], ring[d], q10); }
#pragma unroll
    for (int d = 8; d < 13; ++d) { s5  += ring[d]; q5  = fmaf(ring[d], ring[d], q5);  }

#pragma unroll
    for (int t = 0; t < TL; ++t) {
        const int j = l0 + t;
        const int ln = j + 11;
        const float vnew = ((unsigned)ln < (unsigned)L_) ? fin(xb[ln * F_]) : 0.0f;

        const float xc = ring[10];
        float acc = 0.0f;
        if (j >= 2 && j <= L_ - 3) {
            const float mean  = s5 * 0.2f;
            const float mean2 = q5 * 0.2f;
            const float var   = fmaxf(fmaf(-mean, mean, mean2), 0.0f);
            acc = fmaf(ws5, (xc - mean) * rsqrtf(var + eps), acc);
        }
        if (j >= 5 && j <= L_ - 5) {
            const float mean  = s10 * 0.1f;
            const float mean2 = q10 * 0.1f;
            const float var   = fmaxf(fmaf(-mean, mean, mean2), 0.0f);
            acc = fmaf(ws10, (xc - mean) * rsqrtf(var + eps), acc);
        }
        if (j >= 10 && j <= L_ - 10) {
            const float mean  = s20 * 0.05f;
            const float mean2 = q20 * 0.05f;
            const float var   = fmaxf(fmaf(-mean, mean, mean2), 0.0f);
            acc = fmaf(ws20, (xc - mean) * rsqrtf(var + eps), acc);
        }
        ob[j * F_] = acc;

        { const float a = ring[13], r = ring[8];  const float d = a - r, p = a + r; s5  += d; q5  = fmaf(d, p, q5);  }
        { const float a = ring[15], r = ring[5];  const float d = a - r, p = a + r; s10 += d; q10 = fmaf(d, p, q10); }
        { const float a = ring[20], r = ring[0];  const float d = a - r, p = a + r; s20 += d; q20 = fmaf(d, p, q20); }

#pragma unroll
        for (int d = 0; d < 20; ++d) ring[d] = ring[d + 1];
        ring[20] = vnew;
    }
}

__global__ __launch_bounds__(256, 8)
void fan_kernel(const float* __restrict__ x,
                const float* __restrict__ w,
                float* __restrict__ out) {
    const int f  = threadIdx.x;           // 0..255 == F
    const int b  = blockIdx.y;
    const int l0 = blockIdx.x * TL;
    const float* xb = x   + (size_t)b * L_ * F_ + f;
    float*       ob = out + (size_t)b * L_ * F_ + f;

    // softmax over the 3 fusion logits (uniform across threads)
    const float w0 = w[0], w1 = w[1], w2 = w[2];
    const float m  = fmaxf(w0, fmaxf(w1, w2));
    const float e0 = expf(w0 - m), e1 = expf(w1 - m), e2 = expf(w2 - m);
    const float inv = 1.0f / (e0 + e1 + e2);
    const float ws5 = e0 * inv, ws10 = e1 * inv, ws20 = e2 * inv;

    // interior: loads l0-10..l0+TL+8 in range and all windows valid.
    if (blockIdx.x != 0 && blockIdx.x != gridDim.x - 1)
        run_interior(xb, ob, l0, ws5, ws10, ws20);
    else
        run_edge(xb, ob, l0, ws5, ws10, ws20);
}

extern "C" void kernel_launch(void* const* d_in, const int* in_sizes, int n_in,
                              void* d_out, int out_size, void* d_ws, size_t ws_size,
                              hipStream_t stream) {
    const float* x = (const float*)d_in[0];
    const float* w = (const float*)d_in[1];
    float* out = (float*)d_out;
    (void)in_sizes; (void)n_in; (void)out_size; (void)d_ws; (void)ws_size;

    dim3 grid(L_ / TL, B_);   // (128, 32) = 4096 blocks
    dim3 block(F_);           // 256 threads, one per feature column
    hipLaunchKernelGGL(fan_kernel, grid, block, 0, stream, x, w, out);
}

// Round 7
// 33.483 us; speedup vs baseline: 1.3059x; 1.3059x over previous
//
#include <hip/hip_runtime.h>
#include <math.h>

// FrequencyAdaptiveNorm: multi-scale (w=5,10,20) centered sliding-window
// normalization over L, softmax-weighted fusion.
// x: (B=32, L=2048, F=256) f32, weights: (3,) f32, out: same shape.
//
// v7 = v4 (best so far, 34.8us) with ONE change: rsqrtf -> native v_rsq_f32
// via __builtin_amdgcn_rsqf. Without fast-math, libm rsqrtf expands to an
// OCML fixup sequence; x3 per element it was the largest removable VALU
// block (VALUBusy showed ~115 issue-cyc/elem vs ~50 irreducible).
// v3/v5/v6 lessons kept: scalar ring only, full unroll (ring shift = SSA
// renaming), no address-taken locals, no structured prefetch (hipcc sinks
// loads to first use regardless).

#define B_ 32
#define L_ 2048
#define F_ 256
#define TL 32   // L-chunk per block; grid = (64, 32) = 2048 blocks

#define RSQ(x) __builtin_amdgcn_rsqf(x)   // single v_rsq_f32, ~1 ulp

__device__ __forceinline__ float fin(float v) {
    return isfinite(v) ? v : 0.0f;   // nan_to_num(nan=0, +inf=0, -inf=0)
}

template <bool CHECKED>
__device__ __forceinline__ void run_chunk(const float* __restrict__ xb,
                                          float* __restrict__ ob,
                                          const int l0,
                                          const float ws5, const float ws10,
                                          const float ws20) {
    const float eps = 1e-5f;

    // delay line: ring[d] = x[l0-10+d], d = 0..20
    float ring[21];
#pragma unroll
    for (int d = 0; d < 21; ++d) {
        const int l = l0 - 10 + d;
        float v;
        if (CHECKED)
            v = ((unsigned)l < (unsigned)L_) ? xb[l * F_] : 0.0f;
        else
            v = xb[l * F_];
        ring[d] = fin(v);
    }

    // running sums at j=l0: w5=ring[8..12], w10=ring[5..14], w20=ring[0..19]
    float s5 = 0.f, q5 = 0.f, s10 = 0.f, q10 = 0.f, s20 = 0.f, q20 = 0.f;
#pragma unroll
    for (int d = 0; d < 20; ++d) { s20 += ring[d]; q20 = fmaf(ring[d], ring[d], q20); }
#pragma unroll
    for (int d = 5; d < 15; ++d) { s10 += ring[d]; q10 = fmaf(ring[d], ring[d], q10); }
#pragma unroll
    for (int d = 8; d < 13; ++d) { s5  += ring[d]; q5  = fmaf(ring[d], ring[d], q5);  }

#pragma unroll
    for (int t = 0; t < TL; ++t) {
        const int j = l0 + t;

        // prefetch next ring element (independent of loop-carried sums)
        float vnew;
        if (CHECKED) {
            const int ln = j + 11;
            vnew = ((unsigned)ln < (unsigned)L_) ? fin(xb[ln * F_]) : 0.0f;
        } else {
            vnew = fin(xb[(j + 11) * F_]);
        }

        const float xc = ring[10];
        float acc = 0.0f;

        if (!CHECKED || (j >= 2 && j <= L_ - 3)) {          // w=5
            const float mean  = s5 * 0.2f;
            const float mean2 = q5 * 0.2f;
            const float var   = fmaxf(fmaf(-mean, mean, mean2), 0.0f);
            acc = fmaf(ws5, (xc - mean) * RSQ(var + eps), acc);
        }
        if (!CHECKED || (j >= 5 && j <= L_ - 5)) {          // w=10
            const float mean  = s10 * 0.1f;
            const float mean2 = q10 * 0.1f;
            const float var   = fmaxf(fmaf(-mean, mean, mean2), 0.0f);
            acc = fmaf(ws10, (xc - mean) * RSQ(var + eps), acc);
        }
        if (!CHECKED || (j >= 10 && j <= L_ - 10)) {        // w=20
            const float mean  = s20 * 0.05f;
            const float mean2 = q20 * 0.05f;
            const float var   = fmaxf(fmaf(-mean, mean, mean2), 0.0f);
            acc = fmaf(ws20, (xc - mean) * RSQ(var + eps), acc);
        }
        ob[j * F_] = acc;

        // slide windows j -> j+1:  s += a-r;  q += (a-r)(a+r)
        {
            const float a = ring[13], r = ring[8];
            const float d = a - r, p = a + r;
            s5 += d; q5 = fmaf(d, p, q5);
        }
        {
            const float a = ring[15], r = ring[5];
            const float d = a - r, p = a + r;
            s10 += d; q10 = fmaf(d, p, q10);
        }
        {
            const float a = ring[20], r = ring[0];
            const float d = a - r, p = a + r;
            s20 += d; q20 = fmaf(d, p, q20);
        }

        // shift delay line — full unroll makes this pure register renaming
#pragma unroll
        for (int d = 0; d < 20; ++d) ring[d] = ring[d + 1];
        ring[20] = vnew;
    }
}

__global__ __launch_bounds__(256, 8)
void fan_kernel(const float* __restrict__ x,
                const float* __restrict__ w,
                float* __restrict__ out) {
    const int f  = threadIdx.x;           // 0..255 == F
    const int b  = blockIdx.y;
    const int l0 = blockIdx.x * TL;
    const float* xb = x   + (size_t)b * L_ * F_ + f;
    float*       ob = out + (size_t)b * L_ * F_ + f;

    // softmax over the 3 fusion logits (uniform across threads)
    const float w0 = w[0], w1 = w[1], w2 = w[2];
    const float m  = fmaxf(w0, fmaxf(w1, w2));
    const float e0 = expf(w0 - m), e1 = expf(w1 - m), e2 = expf(w2 - m);
    const float inv = 1.0f / (e0 + e1 + e2);
    const float ws5 = e0 * inv, ws10 = e1 * inv, ws20 = e2 * inv;

    // interior blocks: all loads l0-10..l0+TL+10 in range AND all three
    // window validity ranges cover every j in the chunk.
    if (blockIdx.x != 0 && blockIdx.x != gridDim.x - 1)
        run_chunk<false>(xb, ob, l0, ws5, ws10, ws20);
    else
        run_chunk<true>(xb, ob, l0, ws5, ws10, ws20);
}

extern "C" void kernel_launch(void* const* d_in, const int* in_sizes, int n_in,
                              void* d_out, int out_size, void* d_ws, size_t ws_size,
                              hipStream_t stream) {
    const float* x = (const float*)d_in[0];
    const float* w = (const float*)d_in[1];
    float* out = (float*)d_out;
    (void)in_sizes; (void)n_in; (void)out_size; (void)d_ws; (void)ws_size;

    dim3 grid(L_ / TL, B_);   // (64, 32) = 2048 blocks
    dim3 block(F_);           // 256 threads, one per feature column
    hipLaunchKernelGGL(fan_kernel, grid, block, 0, stream, x, w, out);
}